// Round 1
// baseline (82.970 us; speedup 1.0000x reference)
//
#include <hip/hip_runtime.h>

// YOLOv3 head decode: B=dynamic, NA=3 anchors, 76x76 grid, 85 attrs, stride=8.
// in : [B, 255, 76, 76] f32   (c-major, spatial contiguous)
// out: [B, 3*76*76, 85] f32   (attr contiguous)

#define GH 76
#define GW 76
#define NA 3
#define ATTRS 85
#define SPATIAL (GH * GW)          // 5776
#define STRIDEF 8.0f               // 608 / 76
#define NV (ATTRS * (GW / 4))      // 85 * 19 = 1615 float4 ops per tile

__global__ __launch_bounds__(256) void yolo_head_kernel(
    const float* __restrict__ in, float* __restrict__ out) {
    const int gy = blockIdx.x;   // 0..75
    const int a  = blockIdx.y;   // 0..2
    const int b  = blockIdx.z;   // 0..B-1

    // raw anchors (anchor/stride * stride cancels exactly; 8 is a power of 2)
    const float aw = (a == 0) ? 10.0f : (a == 1) ? 16.0f : 33.0f;
    const float ah = (a == 0) ? 13.0f : (a == 1) ? 30.0f : 23.0f;

    __shared__ float tile[GW * ATTRS];  // [gx][c], 25840 B

    // input base for (b, a, c=0, gy, gx=0)
    const float* inb = in + ((size_t)(b * (NA * ATTRS) + a * ATTRS)) * SPATIAL
                          + (size_t)gy * GW;

    const int tid = threadIdx.x;

    // ---- load + transform + LDS transpose ----
    for (int e = tid; e < NV; e += 256) {
        const int c   = e / 19;         // channel 0..84 (magic-mul div)
        const int q   = e - c * 19;     // float4 index within row
        const int gx0 = q * 4;

        const float4 v = *reinterpret_cast<const float4*>(
            inb + (size_t)c * SPATIAL + gx0);
        float r[4] = {v.x, v.y, v.z, v.w};

#pragma unroll
        for (int j = 0; j < 4; ++j) {
            const float x = r[j];
            float val;
            if (c == 0) {
                val = (1.0f / (1.0f + expf(-x)) + (float)(gx0 + j)) * STRIDEF;
            } else if (c == 1) {
                val = (1.0f / (1.0f + expf(-x)) + (float)gy) * STRIDEF;
            } else if (c == 2) {
                val = expf(x) * aw;
            } else if (c == 3) {
                val = expf(x) * ah;
            } else {
                val = 1.0f / (1.0f + expf(-x));
            }
            // stride 85 floats between lanes -> 85 % 32 = 21, gcd(21,32)=1: conflict-free
            tile[(gx0 + j) * ATTRS + c] = val;
        }
    }

    __syncthreads();

    // ---- LDS -> global, fully contiguous float4 stream ----
    // output base for box index (b, a*SPATIAL + gy*GW), attr 0
    float* outb = out + ((size_t)(b * NA + a) * SPATIAL + (size_t)gy * GW) * ATTRS;
    for (int e = tid; e < NV; e += 256) {
        const float4 v = *reinterpret_cast<const float4*>(&tile[e * 4]);
        *reinterpret_cast<float4*>(outb + e * 4) = v;
    }
}

extern "C" void kernel_launch(void* const* d_in, const int* in_sizes, int n_in,
                              void* d_out, int out_size, void* d_ws, size_t ws_size,
                              hipStream_t stream) {
    const float* in = (const float*)d_in[0];
    float* out = (float*)d_out;
    const int B = in_sizes[0] / (NA * ATTRS * SPATIAL);  // 32
    dim3 grid(GH, NA, B);
    yolo_head_kernel<<<grid, 256, 0, stream>>>(in, out);
}

// Round 2
// 81.708 us; speedup vs baseline: 1.0154x; 1.0154x over previous
//
#include <hip/hip_runtime.h>

// YOLOv3 head decode: B=32, NA=3 anchors, 76x76 grid, 85 attrs, stride=8.
// in : [B, 255, 76, 76] f32   (c-major, spatial contiguous)
// out: [B, 3*76*76, 85] f32   (attr contiguous)

#define GH 76
#define GW 76
#define NA 3
#define ATTRS 85
#define SPATIAL (GH * GW)          // 5776
#define STRIDEF 8.0f               // 608 / 76
#define NV (ATTRS * (GW / 4))      // 1615 float4 chunks per tile
#define LOG2E 1.4426950408889634f

// fast sigmoid / exp: v_exp_f32 + v_rcp_f32 (~1 ulp each; threshold is 2e-2 rel)
__device__ __forceinline__ float fast_sigmoid(float x) {
    return __builtin_amdgcn_rcpf(1.0f + __builtin_amdgcn_exp2f(-LOG2E * x));
}
__device__ __forceinline__ float fast_exp(float x) {
    return __builtin_amdgcn_exp2f(LOG2E * x);
}

// 16B-chunk XOR swizzle: spreads the write-side bank bits 2-4.
// Applied identically on write and read, so it's a pure permutation.
__device__ __forceinline__ int swz(int k) { return k ^ ((k >> 3) & 7); }

__global__ __launch_bounds__(256) void yolo_head_kernel(
    const float* __restrict__ in, float* __restrict__ out) {
    const int gy = blockIdx.x;   // 0..75
    const int a  = blockIdx.y;   // 0..2
    const int b  = blockIdx.z;   // 0..B-1

    // raw anchors (anchor/stride * stride cancels exactly)
    const float aw = (a == 0) ? 10.0f : (a == 1) ? 16.0f : 33.0f;
    const float ah = (a == 0) ? 13.0f : (a == 1) ? 30.0f : 23.0f;

    // +4 floats pad: swz() can map chunk 1614 -> 1615
    __shared__ float tile[GW * ATTRS + 4];

    const float* inb = in + ((size_t)(b * (NA * ATTRS) + a * ATTRS)) * SPATIAL
                          + (size_t)gy * GW;

    const int tid = threadIdx.x;

    // ---- load (coalesced float4) + transform + swizzled LDS transpose ----
    for (int e = tid; e < NV; e += 256) {
        const int c   = e / 19;         // channel 0..84
        const int q   = e - c * 19;
        const int gx0 = q * 4;

        const float4 v = *reinterpret_cast<const float4*>(
            inb + (size_t)c * SPATIAL + gx0);
        float r[4] = {v.x, v.y, v.z, v.w};

#pragma unroll
        for (int j = 0; j < 4; ++j) {
            const float x = r[j];
            float val;
            if (c == 0) {
                val = (fast_sigmoid(x) + (float)(gx0 + j)) * STRIDEF;
            } else if (c == 1) {
                val = (fast_sigmoid(x) + (float)gy) * STRIDEF;
            } else if (c == 2) {
                val = fast_exp(x) * aw;
            } else if (c == 3) {
                val = fast_exp(x) * ah;
            } else {
                val = fast_sigmoid(x);
            }
            const int f = (gx0 + j) * ATTRS + c;       // [gx][c] float index
            const int k = f >> 2;                      // 16B chunk
            tile[(swz(k) << 2) | (f & 3)] = val;
        }
    }

    __syncthreads();

    // ---- LDS -> global, contiguous float4 stream (inverse swizzle on read) ----
    float* outb = out + ((size_t)(b * NA + a) * SPATIAL + (size_t)gy * GW) * ATTRS;
    for (int e = tid; e < NV; e += 256) {
        const float4 v = *reinterpret_cast<const float4*>(&tile[swz(e) * 4]);
        *reinterpret_cast<float4*>(outb + e * 4) = v;
    }
}

extern "C" void kernel_launch(void* const* d_in, const int* in_sizes, int n_in,
                              void* d_out, int out_size, void* d_ws, size_t ws_size,
                              hipStream_t stream) {
    const float* in = (const float*)d_in[0];
    float* out = (float*)d_out;
    const int B = in_sizes[0] / (NA * ATTRS * SPATIAL);  // 32
    dim3 grid(GH, NA, B);
    yolo_head_kernel<<<grid, 256, 0, stream>>>(in, out);
}

// Round 4
// 70.691 us; speedup vs baseline: 1.1737x; 1.1559x over previous
//
#include <hip/hip_runtime.h>

// YOLOv3 head decode: B=32, NA=3 anchors, 76x76 grid, 85 attrs, stride=8.
// in : [B, 255, 76, 76] f32   (c-major, spatial contiguous)
// out: [B, 3*76*76, 85] f32   (attr contiguous)

#define GH 76
#define GW 76
#define NA 3
#define ATTRS 85
#define SPATIAL (GH * GW)          // 5776
#define STRIDEF 8.0f               // 608 / 76
#define NV (ATTRS * (GW / 4))      // 1615 float4 chunks per tile
#define LOG2E 1.4426950408889634f

typedef float f32x4 __attribute__((ext_vector_type(4)));  // nontemporal-store-compatible

__device__ __forceinline__ float fast_sigmoid(float x) {
    return __builtin_amdgcn_rcpf(1.0f + __builtin_amdgcn_exp2f(-LOG2E * x));
}
__device__ __forceinline__ float fast_exp(float x) {
    return __builtin_amdgcn_exp2f(LOG2E * x);
}

// 16B-chunk XOR swizzle (same on write & read side -> pure permutation)
__device__ __forceinline__ int swz(int k) { return k ^ ((k >> 3) & 7); }

__global__ __launch_bounds__(512) void yolo_head_kernel(
    const float* __restrict__ in, float* __restrict__ out) {
    const int gy = blockIdx.x;   // 0..75
    const int a  = blockIdx.y;   // 0..2
    const int b  = blockIdx.z;   // 0..B-1

    const float aw = (a == 0) ? 10.0f : (a == 1) ? 16.0f : 33.0f;
    const float ah = (a == 0) ? 13.0f : (a == 1) ? 30.0f : 23.0f;

    // +4 floats pad: swz() can map chunk 1614 -> 1615
    __shared__ float tile[GW * ATTRS + 4];

    const float* inb = in + ((size_t)(b * (NA * ATTRS) + a * ATTRS)) * SPATIAL
                          + (size_t)gy * GW;

    const int tid = threadIdx.x;

    // ---- load (coalesced float4, L3-cached) + transform + swizzled LDS transpose ----
    for (int e = tid; e < NV; e += 512) {
        const int c   = e / 19;         // channel 0..84
        const int q   = e - c * 19;
        const int gx0 = q * 4;

        const f32x4 v = *reinterpret_cast<const f32x4*>(
            inb + (size_t)c * SPATIAL + gx0);

#pragma unroll
        for (int j = 0; j < 4; ++j) {
            const float x = v[j];
            float val;
            if (c == 0) {
                val = (fast_sigmoid(x) + (float)(gx0 + j)) * STRIDEF;
            } else if (c == 1) {
                val = (fast_sigmoid(x) + (float)gy) * STRIDEF;
            } else if (c == 2) {
                val = fast_exp(x) * aw;
            } else if (c == 3) {
                val = fast_exp(x) * ah;
            } else {
                val = fast_sigmoid(x);
            }
            const int f = (gx0 + j) * ATTRS + c;       // [gx][c] float index
            const int k = f >> 2;                      // 16B chunk
            tile[(swz(k) << 2) | (f & 3)] = val;
        }
    }

    __syncthreads();

    // ---- LDS -> global, contiguous float4 stream, NON-TEMPORAL stores ----
    // (bypass L2/L3 so the 188 MB input stays Infinity-Cache resident)
    float* outb = out + ((size_t)(b * NA + a) * SPATIAL + (size_t)gy * GW) * ATTRS;
    for (int e = tid; e < NV; e += 512) {
        const f32x4 v = *reinterpret_cast<const f32x4*>(&tile[swz(e) * 4]);
        __builtin_nontemporal_store(v, reinterpret_cast<f32x4*>(outb + e * 4));
    }
}

extern "C" void kernel_launch(void* const* d_in, const int* in_sizes, int n_in,
                              void* d_out, int out_size, void* d_ws, size_t ws_size,
                              hipStream_t stream) {
    const float* in = (const float*)d_in[0];
    float* out = (float*)d_out;
    const int B = in_sizes[0] / (NA * ATTRS * SPATIAL);  // 32
    dim3 grid(GH, NA, B);
    yolo_head_kernel<<<grid, 512, 0, stream>>>(in, out);
}

// Round 5
// 59.988 us; speedup vs baseline: 1.3831x; 1.1784x over previous
//
#include <hip/hip_runtime.h>
#include <stdint.h>

// YOLOv3 head decode: B=32, NA=3 anchors, 76x76 grid, 85 attrs, stride=8.
// in : [B, 255, 76, 76] f32   (c-major, spatial contiguous)
// out: [B, 3*76*76, 85] f32   (attr contiguous)
//
// Structure: per-block tile = one (b, anchor, gy) row: 85 channels x 76 floats.
//  stage : global -> LDS via global_load_lds DMA (16B/lane), LDS layout
//          [85 rows][24 chunks] (rows padded 19->24), source pre-swizzled with
//          chunk XOR chi(c) so swizzled reads are ~conflict-free (T21 pattern).
//  output: per 16B out-chunk, 4 swizzled ds_read_b32 + transform + NT store.

#define GH 76
#define GW 76
#define NA 3
#define ATTRS 85
#define SPATIAL (GH * GW)          // 5776
#define NOUT 1615                  // 76*85/4 16B chunks per tile (exact)
#define NSLOT 2048                 // 85*24 = 2040 slots, padded to 2048
#define LOG2E 1.4426950408889634f

typedef float f32x4 __attribute__((ext_vector_type(4)));
typedef const __attribute__((address_space(1))) uint32_t gu32;
typedef __attribute__((address_space(3))) uint32_t lu32;

__device__ __forceinline__ int chi(int c) { return (c >> 2) & 7; }

__global__ __launch_bounds__(512) void yolo_head_kernel(
    const float* __restrict__ in, float* __restrict__ out, int nwg) {
    // ---- bijective XCD swizzle (m204): XCD k gets a contiguous work chunk ----
    const int L = blockIdx.x;
    const int q = nwg >> 3, r = nwg & 7, xcd = L & 7;
    const int W = (xcd < r ? xcd * (q + 1) : r * (q + 1) + (xcd - r) * q) + (L >> 3);
    const int gy = W % GH;
    const int a  = (W / GH) % NA;
    const int b  = W / (GH * NA);

    const float aw = (a == 0) ? 10.0f : (a == 1) ? 16.0f : 33.0f;
    const float ah = (a == 0) ? 13.0f : (a == 1) ? 30.0f : 23.0f;

    __shared__ float tile[NSLOT * 4];   // 32 KB -> 4 blocks/CU, 32 waves

    const float* inb = in + ((size_t)(b * (NA * ATTRS) + a * ATTRS)) * SPATIAL
                          + (size_t)gy * GW;
    const int tid  = threadIdx.x;
    const int lane = tid & 63;
    const int wv   = tid >> 6;          // 0..7

    // ---- stage: 32 wave-groups x 64 chunks, DMA direct to LDS ----
#pragma unroll
    for (int k = 0; k < 4; ++k) {
        const int s   = ((wv << 2) + k) * 64 + lane;   // slot 0..2047
        const int c   = s / 24;
        const int u   = s - c * 24;
        const int gcx = u ^ chi(c);                    // source chunk within row
        const bool valid = (gcx < 19) & (c < ATTRS);
        const float* src = valid ? (inb + (size_t)c * SPATIAL + (gcx << 2)) : inb;
        __builtin_amdgcn_global_load_lds((gu32*)src, (lu32*)&tile[s << 2], 16, 0, 0);
    }
    __syncthreads();

    // ---- transform + swizzled transpose-read + NT store ----
    float* outb = out + ((size_t)(b * NA + a) * SPATIAL + (size_t)gy * GW) * ATTRS;
    for (int m = tid; m < NOUT; m += 512) {
        const int f0 = m << 2;          // first output float of this chunk
        const int gx = f0 / 85;
        const int a0 = f0 - gx * 85;    // first attr index
        f32x4 v;
#pragma unroll
        for (int t = 0; t < 4; ++t) {
            int cc = a0 + t, gxx = gx;
            if (cc >= ATTRS) { cc -= ATTRS; gxx += 1; }   // chunk straddles boxes
            const int slot = cc * 24 + ((gxx >> 2) ^ chi(cc));
            const float x  = tile[(slot << 2) | (gxx & 3)];
            const float E   = __builtin_amdgcn_exp2f(LOG2E * x);   // e^x
            const float sig = E * __builtin_amdgcn_rcpf(1.0f + E);
            float val;
            if      (cc == 0) val = (sig + (float)gxx) * 8.0f;
            else if (cc == 1) val = (sig + (float)gy)  * 8.0f;
            else if (cc == 2) val = E * aw;
            else if (cc == 3) val = E * ah;
            else              val = sig;
            v[t] = val;
        }
        __builtin_nontemporal_store(v, reinterpret_cast<f32x4*>(outb + f0));
    }
}

extern "C" void kernel_launch(void* const* d_in, const int* in_sizes, int n_in,
                              void* d_out, int out_size, void* d_ws, size_t ws_size,
                              hipStream_t stream) {
    const float* in = (const float*)d_in[0];
    float* out = (float*)d_out;
    const int B = in_sizes[0] / (NA * ATTRS * SPATIAL);  // 32
    const int nwg = GH * NA * B;                         // 7296
    yolo_head_kernel<<<dim3(nwg), 512, 0, stream>>>(in, out, nwg);
}